// Round 1
// baseline (378.146 us; speedup 1.0000x reference)
//
#include <hip/hip_runtime.h>
#include <hip/hip_bf16.h>

#define N_TOK 8192
#define DM    1024
#define DH    4096
#define NE    8
#define CAP   1281
#define CAPR  1408   // 11 * 128

typedef unsigned short u16;
typedef __attribute__((ext_vector_type(8))) __bf16 bf16x8;
typedef __attribute__((ext_vector_type(8))) short short8;
typedef __attribute__((ext_vector_type(4))) float f4;

__device__ __forceinline__ u16 f2bf(float f){
  union { float f; unsigned u; } v; v.f = f;
  unsigned r = v.u + 0x7fffu + ((v.u >> 16) & 1u);
  return (u16)(r >> 16);
}

__device__ __forceinline__ float gelu_t(float v){
  return 0.5f * v * (1.f + tanhf(0.7978845608028654f * (v + 0.044715f * v * v * v)));
}

__device__ __forceinline__ void gl2lds16(const void* g, void* l){
  __builtin_amdgcn_global_load_lds((const __attribute__((address_space(1))) void*)g,
                                   (__attribute__((address_space(3))) void*)l, 16, 0, 0);
}

// ---------------- x -> bf16 ----------------
__global__ __launch_bounds__(256) void cvt_x_k(const float* __restrict__ in, u16* __restrict__ out){
  int i = blockIdx.x * 256 + threadIdx.x;
  const f4* p = (const f4*)in + (size_t)i * 2;
  f4 a = p[0], b = p[1];
  short8 o;
  o[0]=(short)f2bf(a[0]); o[1]=(short)f2bf(a[1]); o[2]=(short)f2bf(a[2]); o[3]=(short)f2bf(a[3]);
  o[4]=(short)f2bf(b[0]); o[5]=(short)f2bf(b[1]); o[6]=(short)f2bf(b[2]); o[7]=(short)f2bf(b[3]);
  *(short8*)(out + (size_t)i*8) = o;
}

// ------------- W [e][K][N] f32 -> WT [e][N][K] bf16 -------------
__global__ __launch_bounds__(256) void tcvt_k(const float* __restrict__ in, u16* __restrict__ out,
                                              int K, int Nn){
  __shared__ float tile[64][65];
  size_t mb = (size_t)blockIdx.z * (size_t)K * (size_t)Nn;
  const float* ip = in + mb;
  u16* op = out + mb;
  int n0 = blockIdx.x*64, k0 = blockIdx.y*64;
  int tx = threadIdx.x & 63, ty = threadIdx.x >> 6;
  #pragma unroll
  for (int i=0;i<16;i++){
    int r = ty*16 + i;
    tile[r][tx] = ip[(size_t)(k0+r)*Nn + n0 + tx];
  }
  __syncthreads();
  #pragma unroll
  for (int i=0;i<16;i++){
    int r = ty*16 + i;
    op[(size_t)(n0+r)*K + k0 + tx] = f2bf(tile[tx][r]);
  }
}

// ---------------- router (f32 exact) ----------------
__global__ __launch_bounds__(256) void router_k(const float* __restrict__ x, const float* __restrict__ Wr,
    const float* __restrict__ br, int* __restrict__ top1, float* __restrict__ wgt,
    float* __restrict__ impSum){
  __shared__ float pSh[4][8];
  int wid = threadIdx.x >> 6, lane = threadIdx.x & 63;
  int n = blockIdx.x * 4 + wid;
  const float* xr = x + (size_t)n * DM;
  float acc[8];
  #pragma unroll
  for (int e=0;e<8;e++) acc[e]=0.f;
  #pragma unroll
  for (int c=0;c<4;c++){
    int d0 = c*256 + lane*4;
    f4 xv = *(const f4*)(xr + d0);
    #pragma unroll
    for (int j=0;j<4;j++){
      const float* wrow = Wr + (size_t)(d0+j)*NE;
      float xs = xv[j];
      #pragma unroll
      for (int e=0;e<8;e++) acc[e] = fmaf(xs, wrow[e], acc[e]);
    }
  }
  #pragma unroll
  for (int off=32; off>0; off>>=1){
    #pragma unroll
    for (int e=0;e<8;e++) acc[e] += __shfl_down(acc[e], off, 64);
  }
  if (lane==0){
    float lg[8]; float mx = -1e30f;
    #pragma unroll
    for (int e=0;e<8;e++){ lg[e] = acc[e] + br[e]; mx = fmaxf(mx, lg[e]); }
    float p[8], s=0.f;
    #pragma unroll
    for (int e=0;e<8;e++){ p[e] = expf(lg[e]-mx); s += p[e]; }
    int bt=0; float bv=lg[0];
    #pragma unroll
    for (int e=1;e<8;e++){ if (lg[e]>bv){ bv=lg[e]; bt=e; } }
    float inv = 1.f/s;
    top1[n] = bt; wgt[n] = p[bt]*inv;
    #pragma unroll
    for (int e=0;e<8;e++) pSh[wid][e] = p[e]*inv;
  }
  __syncthreads();
  if (threadIdx.x < 8){
    int e = threadIdx.x;
    atomicAdd(&impSum[e], pSh[0][e]+pSh[1][e]+pSh[2][e]+pSh[3][e]);
  }
}

// ---------------- capacity scan (token order), aux ----------------
__global__ __launch_bounds__(1024) void scan_k(const int* __restrict__ top1, int* __restrict__ idx,
    int* __restrict__ cnt, int* __restrict__ rawcnt, int* __restrict__ dropList,
    int* __restrict__ nDrop, const float* __restrict__ impSum, float* __restrict__ auxOut){
  __shared__ int waveCnt[16][8];
  __shared__ int wavePre[16][8];
  __shared__ int chunkTot[8];
  __shared__ int base_s[8];
  int tid = threadIdx.x, wid = tid>>6, lane = tid&63;
  if (tid < 8) base_s[tid] = 0;
  __syncthreads();
  for (int c=0;c<8;c++){
    int t = c*1024 + tid;
    int e = top1[t];
    int myPre = 0;
    #pragma unroll
    for (int ex=0; ex<8; ex++){
      unsigned long long mk = __ballot(e == ex);
      if (lane == 0) waveCnt[wid][ex] = __popcll(mk);
      if (ex == e) myPre = __popcll(mk & ((1ull<<lane)-1ull));
    }
    __syncthreads();
    if (tid < 8){
      int run = 0;
      for (int wv=0; wv<16; wv++){ wavePre[wv][tid] = run; run += waveCnt[wv][tid]; }
      chunkTot[tid] = run;
    }
    __syncthreads();
    int pos = base_s[e] + wavePre[wid][e] + myPre;
    if (pos < CAP) idx[e*CAPR + pos] = t;
    else { int d = atomicAdd(nDrop, 1); dropList[d] = t; }
    __syncthreads();
    if (tid < 8) base_s[tid] += chunkTot[tid];
    __syncthreads();
  }
  if (tid < 8){
    rawcnt[tid] = base_s[tid];
    cnt[tid] = base_s[tid] < CAP ? base_s[tid] : CAP;
  }
  if (tid == 0){
    float s = 0.f;
    for (int e=0;e<8;e++) s += (impSum[e]*(1.f/N_TOK)) * ((float)base_s[e]*(1.f/N_TOK));
    *auxOut = 0.01f * 8.f * s;
  }
}

// ---------------- zero dropped rows ----------------
__global__ __launch_bounds__(256) void zdrop_k(const int* __restrict__ dropList,
    const int* __restrict__ nDrop, float* __restrict__ y){
  int nd = *nDrop;
  for (int i = blockIdx.x; i < nd; i += gridDim.x){
    int t = dropList[i];
    f4* row = (f4*)(y + (size_t)t * DM);
    f4 z; z[0]=0.f; z[1]=0.f; z[2]=0.f; z[3]=0.f;
    row[threadIdx.x] = z;
  }
}

// ---------------- GEMM1: He = gelu(gather(X) @ W1 + b1), bf16 out ----------------
__global__ __launch_bounds__(256) void gemm1_k(
    const u16* __restrict__ Xb, const u16* __restrict__ W1T,
    const float* __restrict__ b1, const int* __restrict__ idx,
    const int* __restrict__ cnt, u16* __restrict__ He)
{
  int e = blockIdx.z, mt = blockIdx.y, nt = blockIdx.x;
  int cn = cnt[e];
  if (mt*128 >= cn) return;
  __shared__ __align__(16) u16 As[128*64];
  __shared__ __align__(16) u16 Bs[128*64];
  int tid = threadIdx.x, lane = tid&63, wid = tid>>6;
  int arow = tid>>3, acb = tid&7;

  const u16* aS[4]; const u16* bS[4];
  #pragma unroll
  for (int c=0;c<4;c++){
    int row = c*32 + arow;
    int gcb = acb ^ (row&7);                      // T2 swizzle: pre-swizzled source
    int slot = mt*128 + row;
    int token = (slot < cn) ? idx[e*CAPR + slot] : idx[e*CAPR];
    aS[c] = Xb + (size_t)token*DM + gcb*8;
    bS[c] = W1T + ((size_t)e*DH + nt*128 + row)*DM + gcb*8;
  }
  f4 acc[4][4];
  #pragma unroll
  for (int m=0;m<4;m++)
    #pragma unroll
    for (int n=0;n<4;n++)
      #pragma unroll
      for (int j=0;j<4;j++) acc[m][n][j]=0.f;

  int waveM = wid>>1, waveN = wid&1;
  int rA = lane&15, kb = lane>>4;

  for (int kt=0; kt<DM/64; kt++){
    #pragma unroll
    for (int c=0;c<4;c++){
      gl2lds16(aS[c] + kt*64, &As[c*2048 + tid*8]);
      gl2lds16(bS[c] + kt*64, &Bs[c*2048 + tid*8]);
    }
    __syncthreads();
    #pragma unroll
    for (int kk=0;kk<2;kk++){
      bf16x8 af[4], bf_[4];
      #pragma unroll
      for (int m=0;m<4;m++){
        int row = waveM*64 + m*16 + rA;
        int ch = (kk*4+kb) ^ (row&7);
        af[m] = *(const bf16x8*)&As[row*64 + ch*8];
      }
      #pragma unroll
      for (int n=0;n<4;n++){
        int col = waveN*64 + n*16 + rA;
        int ch = (kk*4+kb) ^ (col&7);
        bf_[n] = *(const bf16x8*)&Bs[col*64 + ch*8];
      }
      #pragma unroll
      for (int m=0;m<4;m++)
        #pragma unroll
        for (int n=0;n<4;n++)
          acc[m][n] = __builtin_amdgcn_mfma_f32_16x16x32_bf16(af[m], bf_[n], acc[m][n], 0,0,0);
    }
    __syncthreads();
  }
  int rG = lane>>4;
  #pragma unroll
  for (int n=0;n<4;n++){
    int col = nt*128 + waveN*64 + n*16 + rA;
    float bias = b1[e*DH + col];
    #pragma unroll
    for (int m=0;m<4;m++){
      int slot = mt*128 + waveM*64 + m*16 + rG*4;
      u16* dst = He + ((size_t)e*CAPR + slot)*DH + col;
      #pragma unroll
      for (int j=0;j<4;j++){
        float v = acc[m][n][j] + bias;
        dst[(size_t)j*DH] = f2bf(gelu_t(v));
      }
    }
  }
}

// ---------------- GEMM2: y[token] = (He @ W2 + b2) * w, scatter ----------------
__global__ __launch_bounds__(256) void gemm2_k(
    const u16* __restrict__ He, const u16* __restrict__ W2T,
    const float* __restrict__ b2, const int* __restrict__ idx,
    const int* __restrict__ cnt, const float* __restrict__ wgt,
    float* __restrict__ y)
{
  int e = blockIdx.z, mt = blockIdx.y, nt = blockIdx.x;
  int cn = cnt[e];
  if (mt*128 >= cn) return;
  __shared__ __align__(16) u16 As[128*64];
  __shared__ __align__(16) u16 Bs[128*64];
  int tid = threadIdx.x, lane = tid&63, wid = tid>>6;
  int arow = tid>>3, acb = tid&7;

  const u16* aS[4]; const u16* bS[4];
  #pragma unroll
  for (int c=0;c<4;c++){
    int row = c*32 + arow;
    int gcb = acb ^ (row&7);
    aS[c] = He  + ((size_t)e*CAPR + mt*128 + row)*DH + gcb*8;
    bS[c] = W2T + ((size_t)e*DM   + nt*128 + row)*DH + gcb*8;
  }
  f4 acc[4][4];
  #pragma unroll
  for (int m=0;m<4;m++)
    #pragma unroll
    for (int n=0;n<4;n++)
      #pragma unroll
      for (int j=0;j<4;j++) acc[m][n][j]=0.f;

  int waveM = wid>>1, waveN = wid&1;
  int rA = lane&15, kb = lane>>4;

  for (int kt=0; kt<DH/64; kt++){
    #pragma unroll
    for (int c=0;c<4;c++){
      gl2lds16(aS[c] + kt*64, &As[c*2048 + tid*8]);
      gl2lds16(bS[c] + kt*64, &Bs[c*2048 + tid*8]);
    }
    __syncthreads();
    #pragma unroll
    for (int kk=0;kk<2;kk++){
      bf16x8 af[4], bf_[4];
      #pragma unroll
      for (int m=0;m<4;m++){
        int row = waveM*64 + m*16 + rA;
        int ch = (kk*4+kb) ^ (row&7);
        af[m] = *(const bf16x8*)&As[row*64 + ch*8];
      }
      #pragma unroll
      for (int n=0;n<4;n++){
        int col = waveN*64 + n*16 + rA;
        int ch = (kk*4+kb) ^ (col&7);
        bf_[n] = *(const bf16x8*)&Bs[col*64 + ch*8];
      }
      #pragma unroll
      for (int m=0;m<4;m++)
        #pragma unroll
        for (int n=0;n<4;n++)
          acc[m][n] = __builtin_amdgcn_mfma_f32_16x16x32_bf16(af[m], bf_[n], acc[m][n], 0,0,0);
    }
    __syncthreads();
  }
  int rG = lane>>4;
  #pragma unroll
  for (int m=0;m<4;m++){
    int slot0 = mt*128 + waveM*64 + m*16 + rG*4;
    #pragma unroll
    for (int j=0;j<4;j++){
      int slot = slot0 + j;
      bool valid = slot < cn;
      int tk = valid ? idx[e*CAPR + slot] : 0;
      float wv = valid ? wgt[tk] : 0.f;
      #pragma unroll
      for (int n=0;n<4;n++){
        int col = nt*128 + waveN*64 + n*16 + rA;
        if (valid) y[(size_t)tk*DM + col] = (acc[m][n][j] + b2[e*DM + col]) * wv;
      }
    }
  }
}

extern "C" void kernel_launch(void* const* d_in, const int* in_sizes, int n_in,
                              void* d_out, int out_size, void* d_ws, size_t ws_size,
                              hipStream_t stream){
  const float* x  = (const float*)d_in[0];
  const float* Wr = (const float*)d_in[1];
  const float* br = (const float*)d_in[2];
  const float* W1 = (const float*)d_in[3];
  const float* b1 = (const float*)d_in[4];
  const float* W2 = (const float*)d_in[5];
  const float* b2 = (const float*)d_in[6];
  float* y = (float*)d_out;

  char* ws = (char*)d_ws;
  u16* Xb  = (u16*)(ws);                                       // 16,777,216 B
  u16* W1T = (u16*)(ws + 16777216ull);                          // 67,108,864 B
  u16* W2T = (u16*)(ws + 16777216ull + 67108864ull);            // 67,108,864 B
  u16* He  = (u16*)(ws + 16777216ull + 2ull*67108864ull);       // 92,274,688 B
  char* tail = ws + 16777216ull + 2ull*67108864ull + (size_t)NE*CAPR*DH*2ull;
  int*   top1 = (int*)(tail);                                   // 32768
  float* wgt  = (float*)(tail + 32768);                         // 32768
  int*   idx  = (int*)(tail + 65536);                           // 45056
  int*   drop = (int*)(tail + 65536 + 45056);                   // 32768
  float* impSum = (float*)(tail + 65536 + 45056 + 32768);       // 32
  int*   nDrop  = (int*)((char*)impSum + 32);
  int*   cnt    = nDrop + 1;
  int*   rawcnt = cnt + 8;

  hipMemsetAsync(impSum, 0, 64, stream);   // zero impSum[8] + nDrop (+ slack)

  cvt_x_k<<<4096, 256, 0, stream>>>(x, Xb);
  tcvt_k<<<dim3(64,16,8), 256, 0, stream>>>(W1, W1T, DM, DH);   // W1 [e][1024][4096] -> [e][4096][1024]
  tcvt_k<<<dim3(16,64,8), 256, 0, stream>>>(W2, W2T, DH, DM);   // W2 [e][4096][1024] -> [e][1024][4096]
  router_k<<<2048, 256, 0, stream>>>(x, Wr, br, top1, wgt, impSum);
  scan_k<<<1, 1024, 0, stream>>>(top1, idx, cnt, rawcnt, drop, nDrop, impSum,
                                 y + (size_t)N_TOK*DM);
  zdrop_k<<<64, 256, 0, stream>>>(drop, nDrop, y);
  gemm1_k<<<dim3(DH/128, CAPR/128, NE), 256, 0, stream>>>(Xb, W1T, b1, idx, cnt, He);
  gemm2_k<<<dim3(DM/128, CAPR/128, NE), 256, 0, stream>>>(He, W2T, b2, idx, cnt, wgt, y);

  (void)in_sizes; (void)n_in; (void)out_size; (void)ws_size;
}

// Round 2
// 376.092 us; speedup vs baseline: 1.0055x; 1.0055x over previous
//
#include <hip/hip_runtime.h>
#include <hip/hip_bf16.h>

#define N_TOK 8192
#define DM    1024
#define DH    4096
#define NE    8
#define CAP   1281
#define CAPR  1408   // He row stride (11*128)
#define ISTR  1536   // idx row stride (6*256)

typedef unsigned short u16;
typedef __attribute__((ext_vector_type(8))) __bf16 bf16x8;
typedef __attribute__((ext_vector_type(8))) short short8;
typedef __attribute__((ext_vector_type(4))) float f4;

__device__ __forceinline__ u16 f2bf(float f){
  union { float f; unsigned u; } v; v.f = f;
  unsigned r = v.u + 0x7fffu + ((v.u >> 16) & 1u);
  return (u16)(r >> 16);
}

__device__ __forceinline__ float gelu_fast(float v){
  float u = 0.7978845608028654f * (v + 0.044715f * v * v * v);
  // gelu(v) = v * sigmoid(2u); one v_exp_f32 + one v_rcp_f32
  return v * __builtin_amdgcn_rcpf(1.0f + __expf(-2.0f * u));
}

__device__ __forceinline__ void gl2lds16(const void* g, void* l){
  __builtin_amdgcn_global_load_lds((const __attribute__((address_space(1))) void*)g,
                                   (__attribute__((address_space(3))) void*)l, 16, 0, 0);
}

// ---------------- x -> bf16 ----------------
__global__ __launch_bounds__(256) void cvt_x_k(const float* __restrict__ in, u16* __restrict__ out){
  int i = blockIdx.x * 256 + threadIdx.x;
  const f4* p = (const f4*)in + (size_t)i * 2;
  f4 a = p[0], b = p[1];
  short8 o;
  o[0]=(short)f2bf(a[0]); o[1]=(short)f2bf(a[1]); o[2]=(short)f2bf(a[2]); o[3]=(short)f2bf(a[3]);
  o[4]=(short)f2bf(b[0]); o[5]=(short)f2bf(b[1]); o[6]=(short)f2bf(b[2]); o[7]=(short)f2bf(b[3]);
  *(short8*)(out + (size_t)i*8) = o;
}

// ------------- W [e][K][N] f32 -> WT [e][N][K] bf16, short8 stores -------------
__global__ __launch_bounds__(256) void tcvt_k(const float* __restrict__ in, u16* __restrict__ out,
                                              int K, int Nn){
  __shared__ float tile[64][68];
  size_t mb = (size_t)blockIdx.z * (size_t)K * (size_t)Nn;
  const float* ip = in + mb;
  u16* op = out + mb;
  int n0 = blockIdx.x*64, k0 = blockIdx.y*64;
  int t = threadIdx.x;
  int kr = t>>4, nc = (t&15)*4;
  #pragma unroll
  for (int ii=0;ii<4;ii++){
    f4 v = *(const f4*)&ip[(size_t)(k0+kr+16*ii)*Nn + n0 + nc];
    tile[kr+16*ii][nc+0] = v[0]; tile[kr+16*ii][nc+1] = v[1];
    tile[kr+16*ii][nc+2] = v[2]; tile[kr+16*ii][nc+3] = v[3];
  }
  __syncthreads();
  int nr = t>>2, kc = (t&3)*16;
  short8 o0, o1;
  #pragma unroll
  for (int c=0;c<8;c++){
    o0[c] = (short)f2bf(tile[kc+c][nr]);
    o1[c] = (short)f2bf(tile[kc+8+c][nr]);
  }
  *(short8*)&op[(size_t)(n0+nr)*K + k0 + kc] = o0;
  *(short8*)&op[(size_t)(n0+nr)*K + k0 + kc + 8] = o1;
}

// ---------------- router (f32 exact) ----------------
__global__ __launch_bounds__(256) void router_k(const float* __restrict__ x, const float* __restrict__ Wr,
    const float* __restrict__ br, int* __restrict__ top1, float* __restrict__ wgt,
    float* __restrict__ impSum){
  __shared__ float pSh[4][8];
  int wid = threadIdx.x >> 6, lane = threadIdx.x & 63;
  int n = blockIdx.x * 4 + wid;
  const float* xr = x + (size_t)n * DM;
  float acc[8];
  #pragma unroll
  for (int e=0;e<8;e++) acc[e]=0.f;
  #pragma unroll
  for (int c=0;c<4;c++){
    int d0 = c*256 + lane*4;
    f4 xv = *(const f4*)(xr + d0);
    #pragma unroll
    for (int j=0;j<4;j++){
      const float* wrow = Wr + (size_t)(d0+j)*NE;
      float xs = xv[j];
      #pragma unroll
      for (int e=0;e<8;e++) acc[e] = fmaf(xs, wrow[e], acc[e]);
    }
  }
  #pragma unroll
  for (int off=32; off>0; off>>=1){
    #pragma unroll
    for (int e=0;e<8;e++) acc[e] += __shfl_down(acc[e], off, 64);
  }
  if (lane==0){
    float lg[8]; float mx = -1e30f;
    #pragma unroll
    for (int e=0;e<8;e++){ lg[e] = acc[e] + br[e]; mx = fmaxf(mx, lg[e]); }
    float p[8], s=0.f;
    #pragma unroll
    for (int e=0;e<8;e++){ p[e] = expf(lg[e]-mx); s += p[e]; }
    int bt=0; float bv=lg[0];
    #pragma unroll
    for (int e=1;e<8;e++){ if (lg[e]>bv){ bv=lg[e]; bt=e; } }
    float inv = 1.f/s;
    top1[n] = bt; wgt[n] = p[bt]*inv;
    #pragma unroll
    for (int e=0;e<8;e++) pSh[wid][e] = p[e]*inv;
  }
  __syncthreads();
  if (threadIdx.x < 8){
    int e = threadIdx.x;
    atomicAdd(&impSum[e], pSh[0][e]+pSh[1][e]+pSh[2][e]+pSh[3][e]);
  }
}

// ---------------- capacity scan (token order), aux ----------------
__global__ __launch_bounds__(1024) void scan_k(const int* __restrict__ top1, int* __restrict__ idx,
    int* __restrict__ cnt, int* __restrict__ rawcnt, int* __restrict__ dropList,
    int* __restrict__ nDrop, const float* __restrict__ impSum, float* __restrict__ auxOut){
  __shared__ int waveCnt[16][8];
  __shared__ int wavePre[16][8];
  __shared__ int chunkTot[8];
  __shared__ int base_s[8];
  int tid = threadIdx.x, wid = tid>>6, lane = tid&63;
  if (tid < 8) base_s[tid] = 0;
  __syncthreads();
  for (int c=0;c<8;c++){
    int t = c*1024 + tid;
    int e = top1[t];
    int myPre = 0;
    #pragma unroll
    for (int ex=0; ex<8; ex++){
      unsigned long long mk = __ballot(e == ex);
      if (lane == 0) waveCnt[wid][ex] = __popcll(mk);
      if (ex == e) myPre = __popcll(mk & ((1ull<<lane)-1ull));
    }
    __syncthreads();
    if (tid < 8){
      int run = 0;
      for (int wv=0; wv<16; wv++){ wavePre[wv][tid] = run; run += waveCnt[wv][tid]; }
      chunkTot[tid] = run;
    }
    __syncthreads();
    int pos = base_s[e] + wavePre[wid][e] + myPre;
    if (pos < CAP) idx[e*ISTR + pos] = t;
    else { int d = atomicAdd(nDrop, 1); dropList[d] = t; }
    __syncthreads();
    if (tid < 8) base_s[tid] += chunkTot[tid];
    __syncthreads();
  }
  if (tid < 8){
    rawcnt[tid] = base_s[tid];
    cnt[tid] = base_s[tid] < CAP ? base_s[tid] : CAP;
  }
  if (tid == 0){
    float s = 0.f;
    for (int e=0;e<8;e++) s += (impSum[e]*(1.f/N_TOK)) * ((float)base_s[e]*(1.f/N_TOK));
    *auxOut = 0.01f * 8.f * s;
  }
}

// ---------------- zero dropped rows ----------------
__global__ __launch_bounds__(256) void zdrop_k(const int* __restrict__ dropList,
    const int* __restrict__ nDrop, float* __restrict__ y){
  int nd = *nDrop;
  for (int i = blockIdx.x; i < nd; i += gridDim.x){
    int t = dropList[i];
    f4* row = (f4*)(y + (size_t)t * DM);
    f4 z; z[0]=0.f; z[1]=0.f; z[2]=0.f; z[3]=0.f;
    row[threadIdx.x] = z;
  }
}

// ======== 256x256x64 8-phase pipelined GEMM machinery ========
// LDS map (u16 units): A0:0  A1:16384  B0:32768  B1:49152   (total 128 KiB)
#define SA(buf, h, kt) do{ \
  gl2lds16(aS[(h)*2+0] + (size_t)(kt)*64, &lds[(buf)*16384 + ((h)*2+0)*4096 + t*8]); \
  gl2lds16(aS[(h)*2+1] + (size_t)(kt)*64, &lds[(buf)*16384 + ((h)*2+1)*4096 + t*8]); }while(0)
#define SBg(buf, h, kt) do{ \
  gl2lds16(bS[(h)*2+0] + (size_t)(kt)*64, &lds[32768 + (buf)*16384 + ((h)*2+0)*4096 + t*8]); \
  gl2lds16(bS[(h)*2+1] + (size_t)(kt)*64, &lds[32768 + (buf)*16384 + ((h)*2+1)*4096 + t*8]); }while(0)

#define LDA(buf, m, kk) (*(const bf16x8*)&lds[(buf)*16384 + (aBase ^ ((kk)*32)) + (m)*1024])
#define LDB(buf, n, kk) (*(const bf16x8*)&lds[32768 + (buf)*16384 + (bBase ^ ((kk)*32)) + (n)*1024])

#define PHASE(buf, q, STAGES, PREBAR) do{ \
  bf16x8 a_[2][2]; \
  if ((q)==0){ \
    _Pragma("unroll") for (int n_=0;n_<4;n_++) \
      _Pragma("unroll") for (int kk_=0;kk_<2;kk_++) Bf[n_][kk_] = LDB(buf, n_, kk_); \
  } \
  _Pragma("unroll") for (int j_=0;j_<2;j_++) \
    _Pragma("unroll") for (int kk_=0;kk_<2;kk_++) a_[j_][kk_] = LDA(buf, 2*(q)+j_, kk_); \
  STAGES; \
  __builtin_amdgcn_s_barrier(); \
  asm volatile("s_waitcnt lgkmcnt(0)" ::: "memory"); \
  __builtin_amdgcn_sched_barrier(0); \
  __builtin_amdgcn_s_setprio(1); \
  _Pragma("unroll") for (int j_=0;j_<2;j_++) \
    _Pragma("unroll") for (int n_=0;n_<4;n_++) \
      _Pragma("unroll") for (int kk_=0;kk_<2;kk_++) \
        acc[2*(q)+j_][n_] = __builtin_amdgcn_mfma_f32_16x16x32_bf16(a_[j_][kk_], Bf[n_][kk_], acc[2*(q)+j_][n_], 0,0,0); \
  __builtin_amdgcn_s_setprio(0); \
  PREBAR; \
  __builtin_amdgcn_s_barrier(); \
}while(0)

#define VMC4 asm volatile("s_waitcnt vmcnt(4)" ::: "memory")
#define NOP2 (void)0

// ---------------- GEMM1: He = gelu(gather(X) @ W1 + b1), bf16 out ----------------
__global__ __launch_bounds__(512, 2) void gemm1_k(
    const u16* __restrict__ Xb, const u16* __restrict__ W1T,
    const float* __restrict__ b1, const int* __restrict__ idx,
    const int* __restrict__ cnt, u16* __restrict__ He)
{
  int e = blockIdx.z, mt = blockIdx.y, nt = blockIdx.x;
  int cn = cnt[e];
  if (mt*256 >= cn) return;
  __shared__ __align__(16) u16 lds[65536];
  int t = threadIdx.x, lane = t&63, wid = t>>6;
  int waveM = wid>>2, waveN = wid&3;
  int rA = lane&15, kb = lane>>4, s = rA&7;

  const u16* aS[4]; const u16* bS[4];
  #pragma unroll
  for (int j=0;j<4;j++){
    int pos = j*512 + t;
    int row = pos>>3, ch = pos&7;
    int gcb = ch ^ (row&7);
    int slotrow = mt*256 + row;
    int token = (slotrow < cn) ? idx[e*ISTR + slotrow] : 0;
    aS[j] = Xb + (size_t)token*DM + gcb*8;
    bS[j] = W1T + ((size_t)e*DH + nt*256 + row)*DM + gcb*8;
  }
  f4 acc[8][4];
  #pragma unroll
  for (int m=0;m<8;m++)
    #pragma unroll
    for (int n=0;n<4;n++)
      #pragma unroll
      for (int j=0;j<4;j++) acc[m][n][j]=0.f;

  int aBase = (waveM*128 + rA)*64 + (kb ^ s)*8;
  int bBase = (waveN*64  + rA)*64 + (kb ^ s)*8;
  bf16x8 Bf[4][2];

  // prologue: b0 <- kt0 (B then A), b1.B <- kt1
  SBg(0,0,0); SBg(0,1,0); SA(0,0,0); SA(0,1,0); SBg(1,0,1); SBg(1,1,1);
  VMC4;
  __builtin_amdgcn_s_barrier();

  const int NT = DM/64;   // 16
  #pragma unroll 1
  for (int i=0;i<NT/2;i++){
    int kt1 = 2*i+1;
    int kt2 = (2*i+2 < NT) ? 2*i+2 : NT-1;
    int kt3 = (2*i+3 < NT) ? 2*i+3 : NT-1;
    PHASE(0,0, SA(1,0,kt1), NOP2);
    PHASE(0,1, { SA(1,1,kt1); SBg(0,0,kt2); }, NOP2);
    PHASE(0,2, SBg(0,1,kt2), NOP2);
    PHASE(0,3, NOP2, VMC4);
    PHASE(1,0, SA(0,0,kt2), NOP2);
    PHASE(1,1, { SA(0,1,kt2); SBg(1,0,kt3); }, NOP2);
    PHASE(1,2, SBg(1,1,kt3), NOP2);
    PHASE(1,3, NOP2, VMC4);
  }
  asm volatile("s_waitcnt vmcnt(0)" ::: "memory");

  int rG = lane>>4;
  #pragma unroll
  for (int n=0;n<4;n++){
    int col = nt*256 + waveN*64 + n*16 + rA;
    float bias = b1[e*DH + col];
    #pragma unroll
    for (int m=0;m<8;m++){
      int slot = mt*256 + waveM*128 + m*16 + rG*4;
      if (slot < CAPR){
        u16* dst = He + ((size_t)e*CAPR + slot)*DH + col;
        #pragma unroll
        for (int j=0;j<4;j++){
          float v = acc[m][n][j] + bias;
          dst[(size_t)j*DH] = f2bf(gelu_fast(v));
        }
      }
    }
  }
}

// ---------------- GEMM2: y[token] = (He @ W2 + b2) * w, scatter ----------------
__global__ __launch_bounds__(512, 2) void gemm2_k(
    const u16* __restrict__ He, const u16* __restrict__ W2T,
    const float* __restrict__ b2, const int* __restrict__ idx,
    const int* __restrict__ cnt, const float* __restrict__ wgt,
    float* __restrict__ y)
{
  int e = blockIdx.z, mt = blockIdx.y, nt = blockIdx.x;
  int cn = cnt[e];
  if (mt*256 >= cn) return;
  __shared__ __align__(16) u16 lds[65536];
  int t = threadIdx.x, lane = t&63, wid = t>>6;
  int waveM = wid>>2, waveN = wid&3;
  int rA = lane&15, kb = lane>>4, s = rA&7;

  const u16* aS[4]; const u16* bS[4];
  #pragma unroll
  for (int j=0;j<4;j++){
    int pos = j*512 + t;
    int row = pos>>3, ch = pos&7;
    int gcb = ch ^ (row&7);
    int srow = mt*256 + row; if (srow >= cn) srow = cn-1;
    aS[j] = He  + ((size_t)e*CAPR + srow)*DH + gcb*8;
    bS[j] = W2T + ((size_t)e*DM + nt*256 + row)*DH + gcb*8;
  }
  f4 acc[8][4];
  #pragma unroll
  for (int m=0;m<8;m++)
    #pragma unroll
    for (int n=0;n<4;n++)
      #pragma unroll
      for (int j=0;j<4;j++) acc[m][n][j]=0.f;

  int aBase = (waveM*128 + rA)*64 + (kb ^ s)*8;
  int bBase = (waveN*64  + rA)*64 + (kb ^ s)*8;
  bf16x8 Bf[4][2];

  SBg(0,0,0); SBg(0,1,0); SA(0,0,0); SA(0,1,0); SBg(1,0,1); SBg(1,1,1);
  VMC4;
  __builtin_amdgcn_s_barrier();

  const int NT = DH/64;   // 64
  #pragma unroll 1
  for (int i=0;i<NT/2;i++){
    int kt1 = 2*i+1;
    int kt2 = (2*i+2 < NT) ? 2*i+2 : NT-1;
    int kt3 = (2*i+3 < NT) ? 2*i+3 : NT-1;
    PHASE(0,0, SA(1,0,kt1), NOP2);
    PHASE(0,1, { SA(1,1,kt1); SBg(0,0,kt2); }, NOP2);
    PHASE(0,2, SBg(0,1,kt2), NOP2);
    PHASE(0,3, NOP2, VMC4);
    PHASE(1,0, SA(0,0,kt2), NOP2);
    PHASE(1,1, { SA(0,1,kt2); SBg(1,0,kt3); }, NOP2);
    PHASE(1,2, SBg(1,1,kt3), NOP2);
    PHASE(1,3, NOP2, VMC4);
  }
  asm volatile("s_waitcnt vmcnt(0)" ::: "memory");

  int rG = lane>>4;
  float bias_[4];
  #pragma unroll
  for (int n=0;n<4;n++) bias_[n] = b2[e*DM + nt*256 + waveN*64 + n*16 + rA];
  #pragma unroll
  for (int m=0;m<8;m++){
    int slot0 = mt*256 + waveM*128 + m*16 + rG*4;
    #pragma unroll
    for (int j=0;j<4;j++){
      int slot = slot0 + j;
      bool valid = slot < cn;
      int tk = valid ? idx[e*ISTR + slot] : 0;
      float wv = valid ? wgt[tk] : 0.f;
      float* yr = y + (size_t)tk*DM;
      #pragma unroll
      for (int n=0;n<4;n++){
        int col = nt*256 + waveN*64 + n*16 + rA;
        if (valid) yr[col] = (acc[m][n][j] + bias_[n]) * wv;
      }
    }
  }
}

extern "C" void kernel_launch(void* const* d_in, const int* in_sizes, int n_in,
                              void* d_out, int out_size, void* d_ws, size_t ws_size,
                              hipStream_t stream){
  const float* x  = (const float*)d_in[0];
  const float* Wr = (const float*)d_in[1];
  const float* br = (const float*)d_in[2];
  const float* W1 = (const float*)d_in[3];
  const float* b1 = (const float*)d_in[4];
  const float* W2 = (const float*)d_in[5];
  const float* b2 = (const float*)d_in[6];
  float* y = (float*)d_out;

  char* ws = (char*)d_ws;
  u16* Xb  = (u16*)(ws);                                        // 16,777,216 B
  u16* W1T = (u16*)(ws + 16777216ull);                          // 67,108,864 B
  u16* W2T = (u16*)(ws + 16777216ull + 67108864ull);            // 67,108,864 B
  u16* He  = (u16*)(ws + 16777216ull + 2ull*67108864ull);       // 92,274,688 B
  char* tail = ws + 16777216ull + 2ull*67108864ull + (size_t)NE*CAPR*DH*2ull;
  int*   top1 = (int*)(tail);                                   // 32768
  float* wgt  = (float*)(tail + 32768);                         // 32768
  int*   idx  = (int*)(tail + 65536);                           // 8*1536*4 = 49152
  int*   drop = (int*)(tail + 65536 + 49152);                   // 32768
  float* impSum = (float*)(tail + 65536 + 49152 + 32768);       // 32
  int*   nDrop  = (int*)((char*)impSum + 32);
  int*   cnt    = nDrop + 1;
  int*   rawcnt = cnt + 8;

  hipMemsetAsync(impSum, 0, 64, stream);   // zero impSum[8] + nDrop (+ slack)

  cvt_x_k<<<4096, 256, 0, stream>>>(x, Xb);
  tcvt_k<<<dim3(64,16,8), 256, 0, stream>>>(W1, W1T, DM, DH);   // W1 -> [e][4096][1024]
  tcvt_k<<<dim3(16,64,8), 256, 0, stream>>>(W2, W2T, DH, DM);   // W2 -> [e][1024][4096]
  router_k<<<2048, 256, 0, stream>>>(x, Wr, br, top1, wgt, impSum);
  scan_k<<<1, 1024, 0, stream>>>(top1, idx, cnt, rawcnt, drop, nDrop, impSum,
                                 y + (size_t)N_TOK*DM);
  zdrop_k<<<64, 256, 0, stream>>>(drop, nDrop, y);
  gemm1_k<<<dim3(DH/256, 6, NE), 512, 0, stream>>>(Xb, W1T, b1, idx, cnt, He);
  gemm2_k<<<dim3(DM/256, 6, NE), 512, 0, stream>>>(He, W2T, b2, idx, cnt, wgt, y);

  (void)in_sizes; (void)n_in; (void)out_size; (void)ws_size;
}

// Round 4
// 356.207 us; speedup vs baseline: 1.0616x; 1.0558x over previous
//
#include <hip/hip_runtime.h>
#include <hip/hip_bf16.h>

#define N_TOK 8192
#define DM    1024
#define DH    4096
#define NE    8
#define CAP   1281
#define CAPR  1408   // He row stride (11*128)
#define ISTR  1536   // idx row stride

typedef unsigned short u16;
typedef __attribute__((ext_vector_type(8))) __bf16 bf16x8;
typedef __attribute__((ext_vector_type(8))) short short8;
typedef __attribute__((ext_vector_type(4))) short s16x4;
typedef __attribute__((ext_vector_type(4))) float f4;

__device__ __forceinline__ u16 f2bf(float f){
  union { float f; unsigned u; } v; v.f = f;
  unsigned r = v.u + 0x7fffu + ((v.u >> 16) & 1u);
  return (u16)(r >> 16);
}

__device__ __forceinline__ float gelu_fast(float v){
  float u = 0.7978845608028654f * (v + 0.044715f * v * v * v);
  return v * __builtin_amdgcn_rcpf(1.0f + __expf(-2.0f * u));
}

__device__ __forceinline__ void gl2lds16(const void* g, void* l){
  __builtin_amdgcn_global_load_lds((const __attribute__((address_space(1))) void*)g,
                                   (__attribute__((address_space(3))) void*)l, 16, 0, 0);
}

// ------------- W [e][K][N] f32 -> WT [e][N][K] bf16, short8 stores -------------
__global__ __launch_bounds__(256) void tcvt_k(const float* __restrict__ in, u16* __restrict__ out,
                                              int K, int Nn){
  __shared__ float tile[64][68];
  size_t mb = (size_t)blockIdx.z * (size_t)K * (size_t)Nn;
  const float* ip = in + mb;
  u16* op = out + mb;
  int n0 = blockIdx.x*64, k0 = blockIdx.y*64;
  int t = threadIdx.x;
  int kr = t>>4, nc = (t&15)*4;
  #pragma unroll
  for (int ii=0;ii<4;ii++){
    f4 v = *(const f4*)&ip[(size_t)(k0+kr+16*ii)*Nn + n0 + nc];
    tile[kr+16*ii][nc+0] = v[0]; tile[kr+16*ii][nc+1] = v[1];
    tile[kr+16*ii][nc+2] = v[2]; tile[kr+16*ii][nc+3] = v[3];
  }
  __syncthreads();
  int nr = t>>2, kc = (t&3)*16;
  short8 o0, o1;
  #pragma unroll
  for (int c=0;c<8;c++){
    o0[c] = (short)f2bf(tile[kc+c][nr]);
    o1[c] = (short)f2bf(tile[kc+8+c][nr]);
  }
  *(short8*)&op[(size_t)(n0+nr)*K + k0 + kc] = o0;
  *(short8*)&op[(size_t)(n0+nr)*K + k0 + kc + 8] = o1;
}

// ---------------- router (f32 exact) + fused x->bf16 ----------------
__global__ __launch_bounds__(256) void router_k(const float* __restrict__ x, const float* __restrict__ Wr,
    const float* __restrict__ br, u16* __restrict__ Xb, int* __restrict__ top1,
    float* __restrict__ wgt, float* __restrict__ impSum){
  __shared__ float pSh[4][8];
  int wid = threadIdx.x >> 6, lane = threadIdx.x & 63;
  int n = blockIdx.x * 4 + wid;
  const float* xr = x + (size_t)n * DM;
  u16* xbr = Xb + (size_t)n * DM;
  float acc[8];
  #pragma unroll
  for (int e=0;e<8;e++) acc[e]=0.f;
  #pragma unroll
  for (int c=0;c<4;c++){
    int d0 = c*256 + lane*4;
    f4 xv = *(const f4*)(xr + d0);
    s16x4 xb;
    #pragma unroll
    for (int j=0;j<4;j++) xb[j] = (short)f2bf(xv[j]);
    *(s16x4*)(xbr + d0) = xb;
    #pragma unroll
    for (int j=0;j<4;j++){
      const float* wrow = Wr + (size_t)(d0+j)*NE;
      float xs = xv[j];
      #pragma unroll
      for (int e=0;e<8;e++) acc[e] = fmaf(xs, wrow[e], acc[e]);
    }
  }
  #pragma unroll
  for (int off=32; off>0; off>>=1){
    #pragma unroll
    for (int e=0;e<8;e++) acc[e] += __shfl_down(acc[e], off, 64);
  }
  if (lane==0){
    float lg[8]; float mx = -1e30f;
    #pragma unroll
    for (int e=0;e<8;e++){ lg[e] = acc[e] + br[e]; mx = fmaxf(mx, lg[e]); }
    float p[8], s=0.f;
    #pragma unroll
    for (int e=0;e<8;e++){ p[e] = expf(lg[e]-mx); s += p[e]; }
    int bt=0; float bv=lg[0];
    #pragma unroll
    for (int e=1;e<8;e++){ if (lg[e]>bv){ bv=lg[e]; bt=e; } }
    float inv = 1.f/s;
    top1[n] = bt; wgt[n] = p[bt]*inv;
    #pragma unroll
    for (int e=0;e<8;e++) pSh[wid][e] = p[e]*inv;
  }
  __syncthreads();
  if (threadIdx.x < 8){
    int e = threadIdx.x;
    atomicAdd(&impSum[e], pSh[0][e]+pSh[1][e]+pSh[2][e]+pSh[3][e]);
  }
}

// ---------------- capacity scan (token order), aux ----------------
__global__ __launch_bounds__(1024) void scan_k(const int* __restrict__ top1, int* __restrict__ idx,
    int* __restrict__ cnt, int* __restrict__ rawcnt, int* __restrict__ dropList,
    int* __restrict__ nDrop, const float* __restrict__ impSum, float* __restrict__ auxOut){
  __shared__ int waveCnt[16][8];
  __shared__ int wavePre[16][8];
  __shared__ int chunkTot[8];
  __shared__ int base_s[8];
  int tid = threadIdx.x, wid = tid>>6, lane = tid&63;
  if (tid < 8) base_s[tid] = 0;
  __syncthreads();
  for (int c=0;c<8;c++){
    int t = c*1024 + tid;
    int e = top1[t];
    int myPre = 0;
    #pragma unroll
    for (int ex=0; ex<8; ex++){
      unsigned long long mk = __ballot(e == ex);
      if (lane == 0) waveCnt[wid][ex] = __popcll(mk);
      if (ex == e) myPre = __popcll(mk & ((1ull<<lane)-1ull));
    }
    __syncthreads();
    if (tid < 8){
      int run = 0;
      for (int wv=0; wv<16; wv++){ wavePre[wv][tid] = run; run += waveCnt[wv][tid]; }
      chunkTot[tid] = run;
    }
    __syncthreads();
    int pos = base_s[e] + wavePre[wid][e] + myPre;
    if (pos < CAP) idx[e*ISTR + pos] = t;
    else { int d = atomicAdd(nDrop, 1); dropList[d] = t; }
    __syncthreads();
    if (tid < 8) base_s[tid] += chunkTot[tid];
    __syncthreads();
  }
  if (tid < 8){
    rawcnt[tid] = base_s[tid];
    cnt[tid] = base_s[tid] < CAP ? base_s[tid] : CAP;
  }
  if (tid == 0){
    float s = 0.f;
    for (int e=0;e<8;e++) s += (impSum[e]*(1.f/N_TOK)) * ((float)base_s[e]*(1.f/N_TOK));
    *auxOut = 0.01f * 8.f * s;
  }
}

// ---------------- zero dropped rows ----------------
__global__ __launch_bounds__(256) void zdrop_k(const int* __restrict__ dropList,
    const int* __restrict__ nDrop, float* __restrict__ y){
  int nd = *nDrop;
  for (int i = blockIdx.x; i < nd; i += gridDim.x){
    int t = dropList[i];
    f4* row = (f4*)(y + (size_t)t * DM);
    f4 z; z[0]=0.f; z[1]=0.f; z[2]=0.f; z[3]=0.f;
    row[threadIdx.x] = z;
  }
}

// ======== 256x256x64 GEMM: 4-phase/K-tile, deep stage leads, counted vmcnt ========
// LDS (u16 units): A0:0  A1:16384  B0:32768  B1:49152   (128 KiB)
// Stage groups: group(g) = { SB(g) 4, SAj02(g) 2, SAj13(g) 2 } -> buf g%2.
// Issue: SAj13(kt+1)@kt.ph0, SB(kt+2)@kt.ph1, SAj02(kt+2)@kt.ph2.
// One vmcnt(6) per K-tile (before ph0 barrier) drains exactly group(kt).

#define LDA(buf, m, kk) (*(const bf16x8*)&lds[(buf)*16384 + (aBase ^ ((kk)*32)) + (m)*1024])
#define LDB(buf, n, kk) (*(const bf16x8*)&lds[32768 + (buf)*16384 + (bBase ^ ((kk)*32)) + (n)*1024])

#define SA_J(buf, j, kc) gl2lds16(aS[j] + (size_t)(kc)*64, &lds[(buf)*16384 + ((j)*512 + t)*8])
#define SB_ALLM(buf, kc) do{ \
  gl2lds16(bS[0] + (size_t)(kc)*64, &lds[32768 + (buf)*16384 + (0*512 + t)*8]); \
  gl2lds16(bS[1] + (size_t)(kc)*64, &lds[32768 + (buf)*16384 + (1*512 + t)*8]); \
  gl2lds16(bS[2] + (size_t)(kc)*64, &lds[32768 + (buf)*16384 + (2*512 + t)*8]); \
  gl2lds16(bS[3] + (size_t)(kc)*64, &lds[32768 + (buf)*16384 + (3*512 + t)*8]); }while(0)

#define LGKM0 do{ asm volatile("s_waitcnt lgkmcnt(0)" ::: "memory"); \
                  __builtin_amdgcn_sched_barrier(0); }while(0)

#define MFMA_PAIR(q) \
  _Pragma("unroll") for (int j_=0;j_<2;j_++) \
    _Pragma("unroll") for (int n_=0;n_<4;n_++) \
      _Pragma("unroll") for (int kk_=0;kk_<2;kk_++) \
        acc[2*(q)+j_][n_] = __builtin_amdgcn_mfma_f32_16x16x32_bf16(a_[j_][kk_], Bf[n_][kk_], acc[2*(q)+j_][n_], 0,0,0);

#define KTILE(buf, ktv, NTv) do{ \
  int kc1 = (ktv)+1 < (NTv) ? (ktv)+1 : (NTv)-1; \
  int kc2 = (ktv)+2 < (NTv) ? (ktv)+2 : (NTv)-1; \
  bf16x8 a_[2][2]; \
  /* phase 0: vmcnt BEFORE barrier (cross-wave visibility of group(kt)) */ \
  asm volatile("s_waitcnt vmcnt(6)" ::: "memory"); \
  __builtin_amdgcn_s_barrier(); \
  _Pragma("unroll") for (int n_=0;n_<4;n_++){ Bf[n_][0] = LDB(buf,n_,0); Bf[n_][1] = LDB(buf,n_,1); } \
  a_[0][0]=LDA(buf,0,0); a_[0][1]=LDA(buf,0,1); a_[1][0]=LDA(buf,1,0); a_[1][1]=LDA(buf,1,1); \
  SA_J((buf)^1, 1, kc1); SA_J((buf)^1, 3, kc1); \
  LGKM0; \
  __builtin_amdgcn_s_setprio(1); MFMA_PAIR(0); __builtin_amdgcn_s_setprio(0); \
  /* phase 1 */ \
  __builtin_amdgcn_s_barrier(); \
  a_[0][0]=LDA(buf,2,0); a_[0][1]=LDA(buf,2,1); a_[1][0]=LDA(buf,3,0); a_[1][1]=LDA(buf,3,1); \
  SB_ALLM(buf, kc2); \
  LGKM0; \
  __builtin_amdgcn_s_setprio(1); MFMA_PAIR(1); __builtin_amdgcn_s_setprio(0); \
  /* phase 2 */ \
  __builtin_amdgcn_s_barrier(); \
  a_[0][0]=LDA(buf,4,0); a_[0][1]=LDA(buf,4,1); a_[1][0]=LDA(buf,5,0); a_[1][1]=LDA(buf,5,1); \
  SA_J(buf, 0, kc2); SA_J(buf, 2, kc2); \
  LGKM0; \
  __builtin_amdgcn_s_setprio(1); MFMA_PAIR(2); __builtin_amdgcn_s_setprio(0); \
  /* phase 3 */ \
  __builtin_amdgcn_s_barrier(); \
  a_[0][0]=LDA(buf,6,0); a_[0][1]=LDA(buf,6,1); a_[1][0]=LDA(buf,7,0); a_[1][1]=LDA(buf,7,1); \
  LGKM0; \
  __builtin_amdgcn_s_setprio(1); MFMA_PAIR(3); __builtin_amdgcn_s_setprio(0); \
}while(0)

#define GEMM_PROLOGUE() do{ \
  SB_ALLM(0, 0); \
  SA_J(0,0,0); SA_J(0,2,0); \
  SA_J(0,1,0); SA_J(0,3,0); \
  SB_ALLM(1, 1); \
  SA_J(1,0,1); SA_J(1,2,1); }while(0)

// ---------------- GEMM1: He = gelu(gather(X) @ W1 + b1), bf16 out ----------------
__global__ __launch_bounds__(512, 2) void gemm1_k(
    const u16* __restrict__ Xb, const u16* __restrict__ W1T,
    const float* __restrict__ b1, const int* __restrict__ idx,
    const int* __restrict__ cnt, u16* __restrict__ He)
{
  int e = blockIdx.z, mt = blockIdx.y, nt = blockIdx.x;
  int cn = cnt[e];
  if (mt*256 >= cn) return;
  __shared__ __align__(16) u16 lds[65536];
  int t = threadIdx.x, lane = t&63, wid = t>>6;
  int waveM = wid>>2, waveN = wid&3;
  int rA = lane&15, kb = lane>>4, s = rA&7;

  const u16* aS[4]; const u16* bS[4];
  #pragma unroll
  for (int j=0;j<4;j++){
    int pos = j*512 + t;
    int row = pos>>3, ch = pos&7;
    int gcb = ch ^ (row&7);
    int slotrow = mt*256 + row;
    int token = (slotrow < cn) ? idx[e*ISTR + slotrow] : 0;
    aS[j] = Xb + (size_t)token*DM + gcb*8;
    bS[j] = W1T + ((size_t)e*DH + nt*256 + row)*DM + gcb*8;
  }
  f4 acc[8][4];
  #pragma unroll
  for (int m=0;m<8;m++)
    #pragma unroll
    for (int n=0;n<4;n++)
      #pragma unroll
      for (int j=0;j<4;j++) acc[m][n][j]=0.f;

  int aBase = (waveM*128 + rA)*64 + (kb ^ s)*8;
  int bBase = (waveN*64  + rA)*64 + (kb ^ s)*8;
  bf16x8 Bf[4][2];

  GEMM_PROLOGUE();
  const int NT = DM/64;   // 16
  #pragma unroll 1
  for (int i=0;i<NT/2;i++){
    KTILE(0, 2*i,   NT);
    KTILE(1, 2*i+1, NT);
  }
  asm volatile("s_waitcnt vmcnt(0) lgkmcnt(0)" ::: "memory");

  int rG = lane>>4;
  #pragma unroll
  for (int n=0;n<4;n++){
    int col = nt*256 + waveN*64 + n*16 + rA;
    float bias = b1[e*DH + col];
    #pragma unroll
    for (int m=0;m<8;m++){
      int slot = mt*256 + waveM*128 + m*16 + rG*4;
      if (slot < CAPR){
        u16* dst = He + ((size_t)e*CAPR + slot)*DH + col;
        #pragma unroll
        for (int j=0;j<4;j++){
          float v = acc[m][n][j] + bias;
          dst[(size_t)j*DH] = f2bf(gelu_fast(v));
        }
      }
    }
  }
}

// ---------------- GEMM2: y[token] = (He @ W2 + b2) * w, scatter ----------------
__global__ __launch_bounds__(512, 2) void gemm2_k(
    const u16* __restrict__ He, const u16* __restrict__ W2T,
    const float* __restrict__ b2, const int* __restrict__ idx,
    const int* __restrict__ cnt, const float* __restrict__ wgt,
    float* __restrict__ y)
{
  int e = blockIdx.z, mt = blockIdx.y, nt = blockIdx.x;
  int cn = cnt[e];
  if (mt*256 >= cn) return;
  __shared__ __align__(16) u16 lds[65536];
  int t = threadIdx.x, lane = t&63, wid = t>>6;
  int waveM = wid>>2, waveN = wid&3;
  int rA = lane&15, kb = lane>>4, s = rA&7;

  const u16* aS[4]; const u16* bS[4];
  #pragma unroll
  for (int j=0;j<4;j++){
    int pos = j*512 + t;
    int row = pos>>3, ch = pos&7;
    int gcb = ch ^ (row&7);
    int srow = mt*256 + row; if (srow >= cn) srow = cn-1;
    aS[j] = He  + ((size_t)e*CAPR + srow)*DH + gcb*8;
    bS[j] = W2T + ((size_t)e*DM + nt*256 + row)*DH + gcb*8;
  }
  f4 acc[8][4];
  #pragma unroll
  for (int m=0;m<8;m++)
    #pragma unroll
    for (int n=0;n<4;n++)
      #pragma unroll
      for (int j=0;j<4;j++) acc[m][n][j]=0.f;

  int aBase = (waveM*128 + rA)*64 + (kb ^ s)*8;
  int bBase = (waveN*64  + rA)*64 + (kb ^ s)*8;
  bf16x8 Bf[4][2];

  GEMM_PROLOGUE();
  const int NT = DH/64;   // 64
  #pragma unroll 1
  for (int i=0;i<NT/2;i++){
    KTILE(0, 2*i,   NT);
    KTILE(1, 2*i+1, NT);
  }
  asm volatile("s_waitcnt vmcnt(0) lgkmcnt(0)" ::: "memory");

  int rG = lane>>4;
  float bias_[4];
  #pragma unroll
  for (int n=0;n<4;n++) bias_[n] = b2[e*DM + nt*256 + waveN*64 + n*16 + rA];
  #pragma unroll
  for (int m=0;m<8;m++){
    int slot0 = mt*256 + waveM*128 + m*16 + rG*4;
    #pragma unroll
    for (int j=0;j<4;j++){
      int slot = slot0 + j;
      bool valid = slot < cn;
      int tk = valid ? idx[e*ISTR + slot] : 0;
      float wv = valid ? wgt[tk] : 0.f;
      float* yr = y + (size_t)tk*DM;
      #pragma unroll
      for (int n=0;n<4;n++){
        int col = nt*256 + waveN*64 + n*16 + rA;
        if (valid) yr[col] = (acc[m][n][j] + bias_[n]) * wv;
      }
    }
  }
}

extern "C" void kernel_launch(void* const* d_in, const int* in_sizes, int n_in,
                              void* d_out, int out_size, void* d_ws, size_t ws_size,
                              hipStream_t stream){
  const float* x  = (const float*)d_in[0];
  const float* Wr = (const float*)d_in[1];
  const float* br = (const float*)d_in[2];
  const float* W1 = (const float*)d_in[3];
  const float* b1 = (const float*)d_in[4];
  const float* W2 = (const float*)d_in[5];
  const float* b2 = (const float*)d_in[6];
  float* y = (float*)d_out;

  char* ws = (char*)d_ws;
  u16* Xb  = (u16*)(ws);                                        // 16,777,216 B
  u16* W1T = (u16*)(ws + 16777216ull);                          // 67,108,864 B
  u16* W2T = (u16*)(ws + 16777216ull + 67108864ull);            // 67,108,864 B
  u16* He  = (u16*)(ws + 16777216ull + 2ull*67108864ull);       // 92,274,688 B
  char* tail = ws + 16777216ull + 2ull*67108864ull + (size_t)NE*CAPR*DH*2ull;
  int*   top1 = (int*)(tail);                                   // 32768
  float* wgt  = (float*)(tail + 32768);                         // 32768
  int*   idx  = (int*)(tail + 65536);                           // 8*1536*4 = 49152
  int*   drop = (int*)(tail + 65536 + 49152);                   // 32768
  float* impSum = (float*)(tail + 65536 + 49152 + 32768);       // 32
  int*   nDrop  = (int*)((char*)impSum + 32);
  int*   cnt    = nDrop + 1;
  int*   rawcnt = cnt + 8;

  (void)hipMemsetAsync(impSum, 0, 64, stream);   // zero impSum[8] + nDrop (+ slack)

  tcvt_k<<<dim3(64,16,8), 256, 0, stream>>>(W1, W1T, DM, DH);   // W1 -> [e][4096][1024]
  tcvt_k<<<dim3(16,64,8), 256, 0, stream>>>(W2, W2T, DH, DM);   // W2 -> [e][1024][4096]
  router_k<<<2048, 256, 0, stream>>>(x, Wr, br, Xb, top1, wgt, impSum);
  scan_k<<<1, 1024, 0, stream>>>(top1, idx, cnt, rawcnt, drop, nDrop, impSum,
                                 y + (size_t)N_TOK*DM);
  zdrop_k<<<64, 256, 0, stream>>>(drop, nDrop, y);
  gemm1_k<<<dim3(DH/256, 6, NE), 512, 0, stream>>>(Xb, W1T, b1, idx, cnt, He);
  gemm2_k<<<dim3(DM/256, 6, NE), 512, 0, stream>>>(He, W2T, b2, idx, cnt, wgt, y);

  (void)in_sizes; (void)n_in; (void)out_size; (void)ws_size;
}